// Round 1
// baseline (408.893 us; speedup 1.0000x reference)
//
#include <hip/hip_runtime.h>

typedef __bf16 bf16_t;
typedef __bf16 bf16x8 __attribute__((ext_vector_type(8)));
typedef float f32x4 __attribute__((ext_vector_type(4)));
typedef unsigned short u16;

// ---------- helpers ----------
__device__ __forceinline__ u16 f2bf(float f) {
  unsigned u = __float_as_uint(f);
  unsigned r = (u + 0x7fffu + ((u >> 16) & 1u)) >> 16;
  return (u16)r;
}

typedef const unsigned __attribute__((address_space(1)))* gptr_t;
typedef unsigned __attribute__((address_space(3)))* lptr_t;

__device__ __forceinline__ void gload_lds16(const u16* g, u16* l) {
  __builtin_amdgcn_global_load_lds((gptr_t)(const void*)g, (lptr_t)(void*)l, 16, 0, 0);
}

// ---------- fp32 -> bf16 convert ----------
__global__ __launch_bounds__(256) void cvt_f32_bf16(const float* __restrict__ in,
                                                    u16* __restrict__ out, int n4) {
  int i = blockIdx.x * 256 + threadIdx.x;
  if (i >= n4) return;
  float4 v = reinterpret_cast<const float4*>(in)[i];
  ushort4 o;
  o.x = f2bf(v.x); o.y = f2bf(v.y); o.z = f2bf(v.z); o.w = f2bf(v.w);
  reinterpret_cast<ushort4*>(out)[i] = o;
}

// ---------- adj bit-pack:  [8,1024,1024] int32 -> [8,1024,32] u32 ----------
__global__ __launch_bounds__(256) void pack_adj(const int* __restrict__ adj,
                                                unsigned* __restrict__ bits) {
  unsigned idx = blockIdx.x * 256u + threadIdx.x;   // < 8388608
  int a = adj[idx];
  unsigned long long m = __ballot(a != 0);
  int l = threadIdx.x & 63;
  if ((l & 31) == 0) bits[idx >> 5] = (unsigned)(m >> (l & 32));
}

// ---------- GEMM: out[m,n] = A[m,:] . W[n,:] + bias[n]  (A:[8192,768], W:[768,768] bf16)
// MODE 0: out bf16 [b,h,s,d] = [B*12,1024,64]
// MODE 1: out bf16 transposed per head [b,h,d,s] = [B*12,64,1024]   (for V)
// MODE 2: out fp32 [8192,768] = acc + bias + resid (residual add for O-proj)
template<int MODE>
__global__ __launch_bounds__(256) void gemm_k(
    const u16* __restrict__ A, const u16* __restrict__ W,
    const float* __restrict__ bias, const float* __restrict__ resid,
    u16* __restrict__ outb, float* __restrict__ outf) {
  __shared__ u16 lds[2][2][128 * 32];
  const int tid = threadIdx.x;
  const int w = tid >> 6, l = tid & 63;
  const int bm = blockIdx.x, bn = blockIdx.y;
  const int lr = l & 15, lg = l >> 4;
  const int wm = w >> 1, wn = w & 1;

  const u16* Abase = A + (bm * 128) * 768;
  const u16* Wbase = W + (bn * 128) * 768;

  f32x4 acc[4][4];
#pragma unroll
  for (int i = 0; i < 4; ++i)
#pragma unroll
    for (int j = 0; j < 4; ++j) acc[i][j] = f32x4{0.f, 0.f, 0.f, 0.f};

  auto stage = [&](int buf, int k0) {
#pragma unroll
    for (int r = 0; r < 2; ++r) {
      int rowoff = r * 64 + w * 16;                       // wave-uniform
      const u16* ga = Abase + (rowoff + (l >> 2)) * 768 + k0 + (l & 3) * 8;
      const u16* gw = Wbase + (rowoff + (l >> 2)) * 768 + k0 + (l & 3) * 8;
      gload_lds16(ga, &lds[buf][0][rowoff * 32]);
      gload_lds16(gw, &lds[buf][1][rowoff * 32]);
    }
  };

  stage(0, 0);
  int cur = 0;
  for (int kt = 0; kt < 24; ++kt) {
    __syncthreads();
    if (kt < 23) stage(cur ^ 1, (kt + 1) * 32);
    const u16* la = &lds[cur][0][0];
    const u16* lb = &lds[cur][1][0];
    bf16x8 af[4], bw[4];
#pragma unroll
    for (int i = 0; i < 4; ++i)
      af[i] = *(const bf16x8*)&la[(wm * 64 + i * 16 + lr) * 32 + lg * 8];
#pragma unroll
    for (int j = 0; j < 4; ++j)
      bw[j] = *(const bf16x8*)&lb[(wn * 64 + j * 16 + lr) * 32 + lg * 8];
#pragma unroll
    for (int i = 0; i < 4; ++i)
#pragma unroll
      for (int j = 0; j < 4; ++j)
        acc[i][j] = __builtin_amdgcn_mfma_f32_16x16x32_bf16(af[i], bw[j], acc[i][j], 0, 0, 0);
    cur ^= 1;
  }

  const int m0 = bm * 128 + wm * 64;
  const int n0 = bn * 128 + wn * 64;
#pragma unroll
  for (int i = 0; i < 4; ++i) {
#pragma unroll
    for (int j = 0; j < 4; ++j) {
      int n = n0 + j * 16 + lr;
      float bs = bias[n];
      if (MODE == 0) {
#pragma unroll
        for (int r = 0; r < 4; ++r) {
          int m = m0 + i * 16 + lg * 4 + r;
          int b_ = m >> 10, s_ = m & 1023;
          int h_ = n >> 6, d_ = n & 63;
          outb[((b_ * 12 + h_) * 1024 + s_) * 64 + d_] = f2bf(acc[i][j][r] + bs);
        }
      } else if (MODE == 1) {
        int m = m0 + i * 16 + lg * 4;
        int b_ = m >> 10, s_ = m & 1023;
        int h_ = n >> 6, d_ = n & 63;
        ushort4 o;
        o.x = f2bf(acc[i][j][0] + bs);
        o.y = f2bf(acc[i][j][1] + bs);
        o.z = f2bf(acc[i][j][2] + bs);
        o.w = f2bf(acc[i][j][3] + bs);
        *(ushort4*)&outb[((b_ * 12 + h_) * 64 + d_) * 1024 + s_] = o;
      } else {
#pragma unroll
        for (int r = 0; r < 4; ++r) {
          int m = m0 + i * 16 + lg * 4 + r;
          outf[m * 768 + n] = acc[i][j][r] + bs + resid[m * 768 + n];
        }
      }
    }
  }
}

// ---------- attention: per block = (b,h, 16 q-rows), flash-style over K in tiles of 32 ----------
__global__ __launch_bounds__(64) void attn(
    const u16* __restrict__ Q,   // [96,1024,64]
    const u16* __restrict__ Kt,  // [96,1024,64]
    const u16* __restrict__ VT,  // [96,64,1024]
    const unsigned* __restrict__ bits, // [8,1024,32]
    u16* __restrict__ ctx) {     // [8,1024,768]
  __shared__ u16 plds[16 * 32];
  const int l = threadIdx.x;
  const int lr = l & 15, lg = l >> 4;
  const int blk = blockIdx.x;
  const int qt = blk & 63;
  const int bh = blk >> 6;              // 0..95
  const int b_ = bh / 12, h_ = bh % 12;

  const u16* Qb = Q + (bh * 1024 + qt * 16) * 64;
  const u16* Kb = Kt + bh * 1024 * 64;
  const u16* Vb = VT + bh * 64 * 1024;
  const unsigned* wb = bits + (b_ * 1024 + qt * 16) * 32;

  bf16x8 qa0 = *(const bf16x8*)&Qb[lr * 64 + lg * 8];
  bf16x8 qa1 = *(const bf16x8*)&Qb[lr * 64 + 32 + lg * 8];

  f32x4 cacc[4];
#pragma unroll
  for (int j = 0; j < 4; ++j) cacc[j] = f32x4{0.f, 0.f, 0.f, 0.f};
  float mrun[4] = {-1e30f, -1e30f, -1e30f, -1e30f};
  float lrun[4] = {0.f, 0.f, 0.f, 0.f};

  for (int kt = 0; kt < 32; ++kt) {
    const int k0 = kt * 32;
    f32x4 s0 = f32x4{0.f, 0.f, 0.f, 0.f};
    f32x4 s1 = f32x4{0.f, 0.f, 0.f, 0.f};
    {
      bf16x8 k00 = *(const bf16x8*)&Kb[(k0 + lr) * 64 + lg * 8];
      bf16x8 k01 = *(const bf16x8*)&Kb[(k0 + lr) * 64 + 32 + lg * 8];
      bf16x8 k10 = *(const bf16x8*)&Kb[(k0 + 16 + lr) * 64 + lg * 8];
      bf16x8 k11 = *(const bf16x8*)&Kb[(k0 + 16 + lr) * 64 + 32 + lg * 8];
      s0 = __builtin_amdgcn_mfma_f32_16x16x32_bf16(qa0, k00, s0, 0, 0, 0);
      s0 = __builtin_amdgcn_mfma_f32_16x16x32_bf16(qa1, k01, s0, 0, 0, 0);
      s1 = __builtin_amdgcn_mfma_f32_16x16x32_bf16(qa0, k10, s1, 0, 0, 0);
      s1 = __builtin_amdgcn_mfma_f32_16x16x32_bf16(qa1, k11, s1, 0, 0, 0);
    }
    unsigned wmask[4];
#pragma unroll
    for (int r = 0; r < 4; ++r) wmask[r] = wb[(lg * 4 + r) * 32 + kt];
    float sv0[4], sv1[4];
#pragma unroll
    for (int r = 0; r < 4; ++r) {
      float a0 = s0[r] * 0.125f;
      float a1 = s1[r] * 0.125f;
      sv0[r] = ((wmask[r] >> lr) & 1u) ? a0 : -1e9f;
      sv1[r] = ((wmask[r] >> (16 + lr)) & 1u) ? a1 : -1e9f;
    }
    float alpha[4], p0[4], p1[4];
#pragma unroll
    for (int r = 0; r < 4; ++r) {
      float t = fmaxf(sv0[r], sv1[r]);
      t = fmaxf(t, __shfl_xor(t, 1));
      t = fmaxf(t, __shfl_xor(t, 2));
      t = fmaxf(t, __shfl_xor(t, 4));
      t = fmaxf(t, __shfl_xor(t, 8));
      float mnew = fmaxf(mrun[r], t);
      alpha[r] = __expf(mrun[r] - mnew);
      mrun[r] = mnew;
      p0[r] = __expf(sv0[r] - mnew);
      p1[r] = __expf(sv1[r] - mnew);
      float ps = p0[r] + p1[r];
      ps += __shfl_xor(ps, 1);
      ps += __shfl_xor(ps, 2);
      ps += __shfl_xor(ps, 4);
      ps += __shfl_xor(ps, 8);
      lrun[r] = lrun[r] * alpha[r] + ps;
    }
#pragma unroll
    for (int j = 0; j < 4; ++j)
#pragma unroll
      for (int r = 0; r < 4; ++r) cacc[j][r] *= alpha[r];
    // P (D-layout) -> LDS -> A-layout fragment
#pragma unroll
    for (int r = 0; r < 4; ++r) {
      plds[(lg * 4 + r) * 32 + lr] = f2bf(p0[r]);
      plds[(lg * 4 + r) * 32 + 16 + lr] = f2bf(p1[r]);
    }
    asm volatile("s_waitcnt lgkmcnt(0)" ::: "memory");
    bf16x8 pa = *(const bf16x8*)&plds[lr * 32 + lg * 8];
#pragma unroll
    for (int j = 0; j < 4; ++j) {
      bf16x8 v = *(const bf16x8*)&Vb[(j * 16 + lr) * 1024 + k0 + lg * 8];
      cacc[j] = __builtin_amdgcn_mfma_f32_16x16x32_bf16(pa, v, cacc[j], 0, 0, 0);
    }
  }
  float inv[4];
#pragma unroll
  for (int r = 0; r < 4; ++r) inv[r] = 1.0f / lrun[r];
#pragma unroll
  for (int j = 0; j < 4; ++j) {
#pragma unroll
    for (int r = 0; r < 4; ++r) {
      int q = qt * 16 + lg * 4 + r;
      ctx[(b_ * 1024 + q) * 768 + h_ * 64 + j * 16 + lr] = f2bf(cacc[j][r] * inv[r]);
    }
  }
}

// ---------- LayerNorm: one wave per row of 768 ----------
__global__ __launch_bounds__(256) void layernorm(const float* __restrict__ x,
                                                 const float* __restrict__ gamma,
                                                 const float* __restrict__ beta,
                                                 float* __restrict__ out) {
  int row = blockIdx.x * 4 + (threadIdx.x >> 6);
  int l = threadIdx.x & 63;
  const float4* xr = (const float4*)(x + row * 768);
  float4 v0 = xr[l], v1 = xr[l + 64], v2 = xr[l + 128];
  float s = v0.x + v0.y + v0.z + v0.w + v1.x + v1.y + v1.z + v1.w + v2.x + v2.y + v2.z + v2.w;
#pragma unroll
  for (int d = 1; d < 64; d <<= 1) s += __shfl_xor(s, d);
  float mu = s * (1.0f / 768.0f);
  float q0, q1, q2, vs = 0.f;
  q0 = v0.x - mu; vs += q0 * q0; q0 = v0.y - mu; vs += q0 * q0;
  q0 = v0.z - mu; vs += q0 * q0; q0 = v0.w - mu; vs += q0 * q0;
  q1 = v1.x - mu; vs += q1 * q1; q1 = v1.y - mu; vs += q1 * q1;
  q1 = v1.z - mu; vs += q1 * q1; q1 = v1.w - mu; vs += q1 * q1;
  q2 = v2.x - mu; vs += q2 * q2; q2 = v2.y - mu; vs += q2 * q2;
  q2 = v2.z - mu; vs += q2 * q2; q2 = v2.w - mu; vs += q2 * q2;
#pragma unroll
  for (int d = 1; d < 64; d <<= 1) vs += __shfl_xor(vs, d);
  float rs = rsqrtf(vs * (1.0f / 768.0f) + 1e-5f);
  const float4* g4 = (const float4*)gamma;
  const float4* b4 = (const float4*)beta;
  float4 o;
  float4 g = g4[l], bb = b4[l];
  o.x = (v0.x - mu) * rs * g.x + bb.x; o.y = (v0.y - mu) * rs * g.y + bb.y;
  o.z = (v0.z - mu) * rs * g.z + bb.z; o.w = (v0.w - mu) * rs * g.w + bb.w;
  ((float4*)(out + row * 768))[l] = o;
  g = g4[l + 64]; bb = b4[l + 64];
  o.x = (v1.x - mu) * rs * g.x + bb.x; o.y = (v1.y - mu) * rs * g.y + bb.y;
  o.z = (v1.z - mu) * rs * g.z + bb.z; o.w = (v1.w - mu) * rs * g.w + bb.w;
  ((float4*)(out + row * 768))[l + 64] = o;
  g = g4[l + 128]; bb = b4[l + 128];
  o.x = (v2.x - mu) * rs * g.x + bb.x; o.y = (v2.y - mu) * rs * g.y + bb.y;
  o.z = (v2.z - mu) * rs * g.z + bb.z; o.w = (v2.w - mu) * rs * g.w + bb.w;
  ((float4*)(out + row * 768))[l + 128] = o;
}

// ---------- launch ----------
extern "C" void kernel_launch(void* const* d_in, const int* in_sizes, int n_in,
                              void* d_out, int out_size, void* d_ws, size_t ws_size,
                              hipStream_t stream) {
  (void)in_sizes; (void)n_in; (void)out_size; (void)ws_size;
  const float* inputs = (const float*)d_in[0];
  const int* adj = (const int*)d_in[1];
  const float* Wq = (const float*)d_in[2];
  const float* bq = (const float*)d_in[3];
  const float* Wk = (const float*)d_in[4];
  const float* bk = (const float*)d_in[5];
  const float* Wv = (const float*)d_in[6];
  const float* bv = (const float*)d_in[7];
  const float* Wo = (const float*)d_in[8];
  const float* bo = (const float*)d_in[9];
  const float* gamma = (const float*)d_in[10];
  const float* beta = (const float*)d_in[11];
  float* out = (float*)d_out;
  char* ws = (char*)d_ws;

  // workspace layout (bytes)
  u16* Xbf = (u16*)(ws + 0);              // 12,582,912  (ctx bf16 aliases this later)
  u16* Wqb = (u16*)(ws + 12582912);       //  1,179,648
  u16* Wkb = (u16*)(ws + 13762560);
  u16* Wvb = (u16*)(ws + 14942208);
  u16* Wob = (u16*)(ws + 16121856);
  u16* Qb  = (u16*)(ws + 17301504);       // 12,582,912  (x fp32 aliases Q+K later)
  u16* Kb  = (u16*)(ws + 29884416);       // 12,582,912
  u16* VTb = (u16*)(ws + 42467328);       // 12,582,912
  unsigned* bits = (unsigned*)(ws + 55050240); // 1,048,576  -> total 56,098,816
  u16* ctxb = (u16*)(ws + 0);
  float* xbuf = (float*)(ws + 17301504);

  cvt_f32_bf16<<<6144, 256, 0, stream>>>(inputs, Xbf, 1572864);
  cvt_f32_bf16<<<576, 256, 0, stream>>>(Wq, Wqb, 147456);
  cvt_f32_bf16<<<576, 256, 0, stream>>>(Wk, Wkb, 147456);
  cvt_f32_bf16<<<576, 256, 0, stream>>>(Wv, Wvb, 147456);
  cvt_f32_bf16<<<576, 256, 0, stream>>>(Wo, Wob, 147456);
  pack_adj<<<32768, 256, 0, stream>>>(adj, bits);

  dim3 gg(64, 6);
  gemm_k<0><<<gg, 256, 0, stream>>>(Xbf, Wqb, bq, nullptr, Qb, nullptr);
  gemm_k<0><<<gg, 256, 0, stream>>>(Xbf, Wkb, bk, nullptr, Kb, nullptr);
  gemm_k<1><<<gg, 256, 0, stream>>>(Xbf, Wvb, bv, nullptr, VTb, nullptr);

  attn<<<6144, 64, 0, stream>>>(Qb, Kb, VTb, bits, ctxb);

  gemm_k<2><<<gg, 256, 0, stream>>>(ctxb, Wob, bo, inputs, nullptr, xbuf);

  layernorm<<<2048, 256, 0, stream>>>(xbuf, gamma, beta, out);
}

// Round 3
// 391.477 us; speedup vs baseline: 1.0445x; 1.0445x over previous
//
#include <hip/hip_runtime.h>

typedef __bf16 bf16_t;
typedef __bf16 bf16x8 __attribute__((ext_vector_type(8)));
typedef float f32x4 __attribute__((ext_vector_type(4)));
typedef unsigned short u16;

// ---------- helpers ----------
__device__ __forceinline__ u16 f2bf(float f) {
  unsigned u = __float_as_uint(f);
  unsigned r = (u + 0x7fffu + ((u >> 16) & 1u)) >> 16;
  return (u16)r;
}

typedef const unsigned __attribute__((address_space(1)))* gptr_t;
typedef unsigned __attribute__((address_space(3)))* lptr_t;

__device__ __forceinline__ void gload_lds16(const u16* g, u16* l) {
  __builtin_amdgcn_global_load_lds((gptr_t)(const void*)g, (lptr_t)(void*)l, 16, 0, 0);
}

#define QSCALE 0.18033688f  // 0.125 * log2(e): folds 1/sqrt(64) and exp->exp2

// ---------- fp32 -> bf16 convert (inputs) ----------
__global__ __launch_bounds__(256) void cvt_f32_bf16(const float* __restrict__ in,
                                                    u16* __restrict__ out, int n4) {
  int i = blockIdx.x * 256 + threadIdx.x;
  if (i >= n4) return;
  float4 v = reinterpret_cast<const float4*>(in)[i];
  ushort4 o;
  o.x = f2bf(v.x); o.y = f2bf(v.y); o.z = f2bf(v.z); o.w = f2bf(v.w);
  reinterpret_cast<ushort4*>(out)[i] = o;
}

// ---------- all 4 weights fp32 -> bf16 in one dispatch ----------
__global__ __launch_bounds__(256) void cvt_w4(const float* __restrict__ Wq,
                                              const float* __restrict__ Wk,
                                              const float* __restrict__ Wv,
                                              const float* __restrict__ Wo,
                                              u16* __restrict__ out) {
  int sel = blockIdx.y;
  const float* in = sel == 0 ? Wq : sel == 1 ? Wk : sel == 2 ? Wv : Wo;
  u16* o = out + sel * 589824;
  int i = blockIdx.x * 256 + threadIdx.x;  // < 147456
  float4 v = reinterpret_cast<const float4*>(in)[i];
  ushort4 ov;
  ov.x = f2bf(v.x); ov.y = f2bf(v.y); ov.z = f2bf(v.z); ov.w = f2bf(v.w);
  reinterpret_cast<ushort4*>(o)[i] = ov;
}

// ---------- adj bit-pack:  [8,1024,1024] int32 -> [8,1024,32] u32 ----------
__global__ __launch_bounds__(256) void pack_adj(const int* __restrict__ adj,
                                                unsigned* __restrict__ bits) {
  unsigned idx = blockIdx.x * 256u + threadIdx.x;   // < 8388608
  int a = adj[idx];
  unsigned long long m = __ballot(a != 0);
  int l = threadIdx.x & 63;
  if ((l & 31) == 0) bits[idx >> 5] = (unsigned)(m >> (l & 32));
}

// ---------- fused QKV GEMM: A[8192,768] x {Wq,Wk,Wv}[768,768]^T + bias ----------
// blockIdx.y in [0,18): 0-5 -> Q (scaled by QSCALE), 6-11 -> K, 12-17 -> V (transposed)
__global__ __launch_bounds__(256) void gemm_qkv(
    const u16* __restrict__ A,
    const u16* __restrict__ Wq, const u16* __restrict__ Wk, const u16* __restrict__ Wv,
    const float* __restrict__ bq, const float* __restrict__ bk, const float* __restrict__ bv,
    u16* __restrict__ Qo, u16* __restrict__ Ko, u16* __restrict__ Vo) {
  __shared__ u16 lds[2][2][128 * 32];
  const int tid = threadIdx.x;
  const int w = tid >> 6, l = tid & 63;
  const int bm = blockIdx.x;
  const int bn = blockIdx.y;
  const int sel = bn / 6;          // 0=Q 1=K 2=V (wave-uniform)
  const int bnl = bn % 6;
  const int lr = l & 15, lg = l >> 4;
  const int wm = w >> 1, wn = w & 1;

  const u16* W = sel == 0 ? Wq : sel == 1 ? Wk : Wv;
  const float* bias = sel == 0 ? bq : sel == 1 ? bk : bv;

  const u16* Abase = A + (bm * 128) * 768;
  const u16* Wbase = W + (bnl * 128) * 768;

  f32x4 acc[4][4];
#pragma unroll
  for (int i = 0; i < 4; ++i)
#pragma unroll
    for (int j = 0; j < 4; ++j) acc[i][j] = f32x4{0.f, 0.f, 0.f, 0.f};

  auto stage = [&](int buf, int k0) {
#pragma unroll
    for (int r = 0; r < 2; ++r) {
      int rowoff = r * 64 + w * 16;                       // wave-uniform
      const u16* ga = Abase + (rowoff + (l >> 2)) * 768 + k0 + (l & 3) * 8;
      const u16* gw = Wbase + (rowoff + (l >> 2)) * 768 + k0 + (l & 3) * 8;
      gload_lds16(ga, &lds[buf][0][rowoff * 32]);
      gload_lds16(gw, &lds[buf][1][rowoff * 32]);
    }
  };

  stage(0, 0);
  int cur = 0;
  for (int kt = 0; kt < 24; ++kt) {
    __syncthreads();
    if (kt < 23) stage(cur ^ 1, (kt + 1) * 32);
    const u16* la = &lds[cur][0][0];
    const u16* lb = &lds[cur][1][0];
    bf16x8 af[4], bw[4];
#pragma unroll
    for (int i = 0; i < 4; ++i)
      af[i] = *(const bf16x8*)&la[(wm * 64 + i * 16 + lr) * 32 + lg * 8];
#pragma unroll
    for (int j = 0; j < 4; ++j)
      bw[j] = *(const bf16x8*)&lb[(wn * 64 + j * 16 + lr) * 32 + lg * 8];
#pragma unroll
    for (int i = 0; i < 4; ++i)
#pragma unroll
      for (int j = 0; j < 4; ++j)
        acc[i][j] = __builtin_amdgcn_mfma_f32_16x16x32_bf16(af[i], bw[j], acc[i][j], 0, 0, 0);
    cur ^= 1;
  }

  const int m0 = bm * 128 + wm * 64;
  const int n0 = bnl * 128 + wn * 64;
#pragma unroll
  for (int i = 0; i < 4; ++i) {
#pragma unroll
    for (int j = 0; j < 4; ++j) {
      int n = n0 + j * 16 + lr;
      float bs = bias[n];
      int h_ = n >> 6, d_ = n & 63;
      if (sel == 2) {
        int m = m0 + i * 16 + lg * 4;
        int b_ = m >> 10, s_ = m & 1023;
        ushort4 o;
        o.x = f2bf(acc[i][j][0] + bs);
        o.y = f2bf(acc[i][j][1] + bs);
        o.z = f2bf(acc[i][j][2] + bs);
        o.w = f2bf(acc[i][j][3] + bs);
        *(ushort4*)&Vo[((b_ * 12 + h_) * 64 + d_) * 1024 + s_] = o;
      } else {
        u16* dst = sel == 0 ? Qo : Ko;
        float sc = sel == 0 ? QSCALE : 1.0f;
#pragma unroll
        for (int r = 0; r < 4; ++r) {
          int m = m0 + i * 16 + lg * 4 + r;
          int b_ = m >> 10, s_ = m & 1023;
          dst[((b_ * 12 + h_) * 1024 + s_) * 64 + d_] = f2bf((acc[i][j][r] + bs) * sc);
        }
      }
    }
  }
}

// ---------- O-proj GEMM: fp32 out = acc + bias + resid ----------
__global__ __launch_bounds__(256) void gemm_o(
    const u16* __restrict__ A, const u16* __restrict__ W,
    const float* __restrict__ bias, const float* __restrict__ resid,
    float* __restrict__ outf) {
  __shared__ u16 lds[2][2][128 * 32];
  const int tid = threadIdx.x;
  const int w = tid >> 6, l = tid & 63;
  const int bm = blockIdx.x, bn = blockIdx.y;
  const int lr = l & 15, lg = l >> 4;
  const int wm = w >> 1, wn = w & 1;

  const u16* Abase = A + (bm * 128) * 768;
  const u16* Wbase = W + (bn * 128) * 768;

  f32x4 acc[4][4];
#pragma unroll
  for (int i = 0; i < 4; ++i)
#pragma unroll
    for (int j = 0; j < 4; ++j) acc[i][j] = f32x4{0.f, 0.f, 0.f, 0.f};

  auto stage = [&](int buf, int k0) {
#pragma unroll
    for (int r = 0; r < 2; ++r) {
      int rowoff = r * 64 + w * 16;
      const u16* ga = Abase + (rowoff + (l >> 2)) * 768 + k0 + (l & 3) * 8;
      const u16* gw = Wbase + (rowoff + (l >> 2)) * 768 + k0 + (l & 3) * 8;
      gload_lds16(ga, &lds[buf][0][rowoff * 32]);
      gload_lds16(gw, &lds[buf][1][rowoff * 32]);
    }
  };

  stage(0, 0);
  int cur = 0;
  for (int kt = 0; kt < 24; ++kt) {
    __syncthreads();
    if (kt < 23) stage(cur ^ 1, (kt + 1) * 32);
    const u16* la = &lds[cur][0][0];
    const u16* lb = &lds[cur][1][0];
    bf16x8 af[4], bw[4];
#pragma unroll
    for (int i = 0; i < 4; ++i)
      af[i] = *(const bf16x8*)&la[(wm * 64 + i * 16 + lr) * 32 + lg * 8];
#pragma unroll
    for (int j = 0; j < 4; ++j)
      bw[j] = *(const bf16x8*)&lb[(wn * 64 + j * 16 + lr) * 32 + lg * 8];
#pragma unroll
    for (int i = 0; i < 4; ++i)
#pragma unroll
      for (int j = 0; j < 4; ++j)
        acc[i][j] = __builtin_amdgcn_mfma_f32_16x16x32_bf16(af[i], bw[j], acc[i][j], 0, 0, 0);
    cur ^= 1;
  }

  const int m0 = bm * 128 + wm * 64;
  const int n0 = bn * 128 + wn * 64;
#pragma unroll
  for (int i = 0; i < 4; ++i) {
#pragma unroll
    for (int j = 0; j < 4; ++j) {
      int n = n0 + j * 16 + lr;
      float bs = bias[n];
#pragma unroll
      for (int r = 0; r < 4; ++r) {
        int m = m0 + i * 16 + lg * 4 + r;
        outf[m * 768 + n] = acc[i][j][r] + bs + resid[m * 768 + n];
      }
    }
  }
}

// ---------- attention, no-max softmax ----------
// block = 256 thr (4 waves), each wave owns 16 q-rows of one (b,h).
// Q pre-scaled by QSCALE in GEMM epilogue -> p = exp2(S) directly.
// Unnormalized ctx + row-sum l via ones-MFMA; divide once at the end.
__global__ __launch_bounds__(256) void attn(
    const u16* __restrict__ Q,   // [96,1024,64]
    const u16* __restrict__ Kt,  // [96,1024,64]
    const u16* __restrict__ VT,  // [96,64,1024]
    const unsigned* __restrict__ bits, // [8,1024,32]
    u16* __restrict__ ctx) {     // [8,1024,768]
  __shared__ u16 plds_all[4][16 * 64];
  const int tid = threadIdx.x;
  const int w = tid >> 6, l = tid & 63;
  const int lr = l & 15, lg = l >> 4;
  const int blk = blockIdx.x;
  const int bh = blk >> 4;                 // 0..95
  const int qt = ((blk & 15) << 2) | w;    // 0..63
  const int b_ = bh / 12, h_ = bh % 12;
  u16* plds = plds_all[w];

  const u16* Qb = Q + (bh * 1024 + qt * 16) * 64;
  const u16* Kb = Kt + bh * 1024 * 64;
  const u16* Vb = VT + bh * 64 * 1024;
  const unsigned* wb = bits + (b_ * 1024 + qt * 16) * 32;

  bf16x8 qa0 = *(const bf16x8*)&Qb[lr * 64 + lg * 8];
  bf16x8 qa1 = *(const bf16x8*)&Qb[lr * 64 + 32 + lg * 8];

  bf16x8 vones;
#pragma unroll
  for (int i = 0; i < 8; ++i) vones[i] = (__bf16)1.0f;

  f32x4 cacc[4];
#pragma unroll
  for (int j = 0; j < 4; ++j) cacc[j] = f32x4{0.f, 0.f, 0.f, 0.f};
  f32x4 lacc = f32x4{0.f, 0.f, 0.f, 0.f};

  for (int kt = 0; kt < 16; ++kt) {
    const int k0 = kt * 64;
    uint2 mm[4];
#pragma unroll
    for (int r = 0; r < 4; ++r)
      mm[r] = *(const uint2*)&wb[(lg * 4 + r) * 32 + kt * 2];

    f32x4 s[4];
#pragma unroll
    for (int t = 0; t < 4; ++t) {
      const u16* kp = &Kb[(k0 + t * 16 + lr) * 64 + lg * 8];
      bf16x8 ka = *(const bf16x8*)kp;
      bf16x8 kb2 = *(const bf16x8*)(kp + 32);
      f32x4 z = f32x4{0.f, 0.f, 0.f, 0.f};
      z = __builtin_amdgcn_mfma_f32_16x16x32_bf16(qa0, ka, z, 0, 0, 0);
      z = __builtin_amdgcn_mfma_f32_16x16x32_bf16(qa1, kb2, z, 0, 0, 0);
      s[t] = z;
    }

    // mask + exp2 + bf16 + swizzled LDS write (row-dependent XOR kills bank conflicts)
#pragma unroll
    for (int r = 0; r < 4; ++r) {
      const int q = lg * 4 + r;
      const int sw = (q & 7) << 3;
      unsigned w0 = mm[r].x >> lr;
      unsigned w1 = mm[r].y >> lr;
#pragma unroll
      for (int t = 0; t < 4; ++t) {
        unsigned bit = (t == 0) ? (w0 & 1u)
                     : (t == 1) ? ((w0 >> 16) & 1u)
                     : (t == 2) ? (w1 & 1u)
                                : ((w1 >> 16) & 1u);
        float sv = bit ? s[t][r] : -1e30f;
        float p = exp2f(sv);
        plds[q * 64 + ((t * 16 + lr) ^ sw)] = f2bf(p);
      }
    }
    asm volatile("s_waitcnt lgkmcnt(0)" ::: "memory");
    const int swr = (lr & 7) << 3;
    bf16x8 pa0 = *(const bf16x8*)&plds[lr * 64 + ((lg * 8) ^ swr)];
    bf16x8 pa1 = *(const bf16x8*)&plds[lr * 64 + ((32 + lg * 8) ^ swr)];

    lacc = __builtin_amdgcn_mfma_f32_16x16x32_bf16(pa0, vones, lacc, 0, 0, 0);
    lacc = __builtin_amdgcn_mfma_f32_16x16x32_bf16(pa1, vones, lacc, 0, 0, 0);
#pragma unroll
    for (int j = 0; j < 4; ++j) {
      const u16* vp = &Vb[(j * 16 + lr) * 1024 + k0 + lg * 8];
      bf16x8 v0 = *(const bf16x8*)vp;
      bf16x8 v1 = *(const bf16x8*)(vp + 32);
      cacc[j] = __builtin_amdgcn_mfma_f32_16x16x32_bf16(pa0, v0, cacc[j], 0, 0, 0);
      cacc[j] = __builtin_amdgcn_mfma_f32_16x16x32_bf16(pa1, v1, cacc[j], 0, 0, 0);
    }
  }

  float inv[4];
#pragma unroll
  for (int r = 0; r < 4; ++r) inv[r] = 1.0f / lacc[r];
#pragma unroll
  for (int j = 0; j < 4; ++j) {
#pragma unroll
    for (int r = 0; r < 4; ++r) {
      int q = qt * 16 + lg * 4 + r;
      ctx[(b_ * 1024 + q) * 768 + h_ * 64 + j * 16 + lr] = f2bf(cacc[j][r] * inv[r]);
    }
  }
}

// ---------- LayerNorm: one wave per row of 768 ----------
__global__ __launch_bounds__(256) void layernorm(const float* __restrict__ x,
                                                 const float* __restrict__ gamma,
                                                 const float* __restrict__ beta,
                                                 float* __restrict__ out) {
  int row = blockIdx.x * 4 + (threadIdx.x >> 6);
  int l = threadIdx.x & 63;
  const float4* xr = (const float4*)(x + row * 768);
  float4 v0 = xr[l], v1 = xr[l + 64], v2 = xr[l + 128];
  float s = v0.x + v0.y + v0.z + v0.w + v1.x + v1.y + v1.z + v1.w + v2.x + v2.y + v2.z + v2.w;
#pragma unroll
  for (int d = 1; d < 64; d <<= 1) s += __shfl_xor(s, d);
  float mu = s * (1.0f / 768.0f);
  float q0, q1, q2, vs = 0.f;
  q0 = v0.x - mu; vs += q0 * q0; q0 = v0.y - mu; vs += q0 * q0;
  q0 = v0.z - mu; vs += q0 * q0; q0 = v0.w - mu; vs += q0 * q0;
  q1 = v1.x - mu; vs += q1 * q1; q1 = v1.y - mu; vs += q1 * q1;
  q1 = v1.z - mu; vs += q1 * q1; q1 = v1.w - mu; vs += q1 * q1;
  q2 = v2.x - mu; vs += q2 * q2; q2 = v2.y - mu; vs += q2 * q2;
  q2 = v2.z - mu; vs += q2 * q2; q2 = v2.w - mu; vs += q2 * q2;
#pragma unroll
  for (int d = 1; d < 64; d <<= 1) vs += __shfl_xor(vs, d);
  float rs = rsqrtf(vs * (1.0f / 768.0f) + 1e-5f);
  const float4* g4 = (const float4*)gamma;
  const float4* b4 = (const float4*)beta;
  float4 o;
  float4 g = g4[l], bb = b4[l];
  o.x = (v0.x - mu) * rs * g.x + bb.x; o.y = (v0.y - mu) * rs * g.y + bb.y;
  o.z = (v0.z - mu) * rs * g.z + bb.z; o.w = (v0.w - mu) * rs * g.w + bb.w;
  ((float4*)(out + row * 768))[l] = o;
  g = g4[l + 64]; bb = b4[l + 64];
  o.x = (v1.x - mu) * rs * g.x + bb.x; o.y = (v1.y - mu) * rs * g.y + bb.y;
  o.z = (v1.z - mu) * rs * g.z + bb.z; o.w = (v1.w - mu) * rs * g.w + bb.w;
  ((float4*)(out + row * 768))[l + 64] = o;
  g = g4[l + 128]; bb = b4[l + 128];
  o.x = (v2.x - mu) * rs * g.x + bb.x; o.y = (v2.y - mu) * rs * g.y + bb.y;
  o.z = (v2.z - mu) * rs * g.z + bb.z; o.w = (v2.w - mu) * rs * g.w + bb.w;
  ((float4*)(out + row * 768))[l + 128] = o;
}

// ---------- launch ----------
extern "C" void kernel_launch(void* const* d_in, const int* in_sizes, int n_in,
                              void* d_out, int out_size, void* d_ws, size_t ws_size,
                              hipStream_t stream) {
  (void)in_sizes; (void)n_in; (void)out_size; (void)ws_size;
  const float* inputs = (const float*)d_in[0];
  const int* adj = (const int*)d_in[1];
  const float* Wq = (const float*)d_in[2];
  const float* bq = (const float*)d_in[3];
  const float* Wk = (const float*)d_in[4];
  const float* bk = (const float*)d_in[5];
  const float* Wv = (const float*)d_in[6];
  const float* bv = (const float*)d_in[7];
  const float* Wo = (const float*)d_in[8];
  const float* bo = (const float*)d_in[9];
  const float* gamma = (const float*)d_in[10];
  const float* beta = (const float*)d_in[11];
  float* out = (float*)d_out;
  char* ws = (char*)d_ws;

  // workspace layout (bytes)
  u16* Xbf = (u16*)(ws + 0);              // 12,582,912  (ctx bf16 aliases this later)
  u16* Wqb = (u16*)(ws + 12582912);       //  4 x 1,179,648 contiguous (cvt_w4)
  u16* Wkb = (u16*)(ws + 13762560);
  u16* Wvb = (u16*)(ws + 14942208);
  u16* Wob = (u16*)(ws + 16121856);
  u16* Qb  = (u16*)(ws + 17301504);       // 12,582,912  (x fp32 aliases Q+K later)
  u16* Kb  = (u16*)(ws + 29884416);       // 12,582,912
  u16* VTb = (u16*)(ws + 42467328);       // 12,582,912
  unsigned* bits = (unsigned*)(ws + 55050240); // 1,048,576  -> total 56,098,816
  u16* ctxb = (u16*)(ws + 0);
  float* xbuf = (float*)(ws + 17301504);

  cvt_f32_bf16<<<6144, 256, 0, stream>>>(inputs, Xbf, 1572864);
  cvt_w4<<<dim3(576, 4), 256, 0, stream>>>(Wq, Wk, Wv, Wo, Wqb);
  pack_adj<<<32768, 256, 0, stream>>>(adj, bits);

  gemm_qkv<<<dim3(64, 18), 256, 0, stream>>>(Xbf, Wqb, Wkb, Wvb, bq, bk, bv, Qb, Kb, VTb);

  attn<<<1536, 256, 0, stream>>>(Qb, Kb, VTb, bits, ctxb);

  gemm_o<<<dim3(64, 6), 256, 0, stream>>>(ctxb, Wob, bo, inputs, xbuf);

  layernorm<<<2048, 256, 0, stream>>>(xbuf, gamma, beta, out);
}